// Round 4
// baseline (102.733 us; speedup 1.0000x reference)
//
#include <hip/hip_runtime.h>

// DAG reachability closure from node 0 (N=8192, <=2 children, -1 = leaf).
// Reference's N relaxation steps == transitive closure; we BFS to fixpoint.
//
// SINGLE-WAVE design (64 threads = 1 wave on 1 CU):
//   - no __shared__ flags, no multi-wave barriers: termination is a free
//     in-register __any() ballot; LDS-atomic visibility across lanes costs
//     one lgkmcnt(0) (1-wave __syncthreads(), ~free — same instr stream).
//     R2/R3 post-mortem: pass mechanics (16/4-wave barriers + LDS flag
//     handshake x ~35 passes) dominated; R3's 32-nodes/thread serial
//     expansion regressed -12 us vs R2's 8/thread.
//   - edges interleaved in LDS as int2 (64 KB): one ds_read_b64 per node
//   - reach bitmask: 256 words LDS; lane owns 4 contiguous words
//     (one ds_read_b128 per pass per lane)
//   - expansion: divergent ffs loop, LDS atomicOr (monotone -> races benign)
// Output: int32 0/1 (harness materializes the bool mask as int32).

#define NMAX 8192
#define BLK  64

__global__ __launch_bounds__(BLK) void dag_reach_kernel(
    const int* __restrict__ left,
    const int* __restrict__ right,
    int* __restrict__ out,
    int n)
{
    __shared__ int2 sLR[NMAX];                              // (left,right) per node
    __shared__ __align__(16) unsigned int reach[NMAX / 32]; // 256 words

    const int lane = threadIdx.x;   // 0..63, one wave

    // ---- stage edges: int4 global loads, int2 LDS writes (32 iters/lane) ----
    {
        const int4* l4 = (const int4*)left;
        const int4* r4 = (const int4*)right;
        const int nv = n / 4;
        for (int i = lane; i < nv; i += BLK) {
            int4 l = l4[i];
            int4 r = r4[i];
            int b = i * 4;
            sLR[b + 0] = make_int2(l.x, r.x);
            sLR[b + 1] = make_int2(l.y, r.y);
            sLR[b + 2] = make_int2(l.z, r.z);
            sLR[b + 3] = make_int2(l.w, r.w);
        }
    }
    // init reach: lane writes its 4 words; seed node 0
    {
        uint4 z = make_uint4(lane == 0 ? 1u : 0u, 0u, 0u, 0u);
        ((uint4*)reach)[lane] = z;
    }
    __syncthreads();   // 1 wave: lgkmcnt drain, barrier ~free

    // ---- BFS to fixpoint, no flags ----
    unsigned int expd0 = 0u, expd1 = 0u, expd2 = 0u, expd3 = 0u;
    const int nbase = lane * 128;   // lane owns nodes [128*lane, 128*lane+128)

    for (;;) {
        uint4 w = ((const uint4*)reach)[lane];    // ds_read_b128
        unsigned int p0 = w.x & ~expd0;
        unsigned int p1 = w.y & ~expd1;
        unsigned int p2 = w.z & ~expd2;
        unsigned int p3 = w.w & ~expd3;
        if (!__any((p0 | p1 | p2 | p3) != 0u)) break;   // free wave ballot
        expd0 |= p0; expd1 |= p1; expd2 |= p2; expd3 |= p3;

        unsigned int pw[4] = {p0, p1, p2, p3};
        #pragma unroll
        for (int wi = 0; wi < 4; ++wi) {
            unsigned int pend = pw[wi];
            const int wb = nbase + wi * 32;
            while (pend) {
                int b = __ffs(pend) - 1;
                pend &= pend - 1;
                int2 lr = sLR[wb + b];
                if (lr.x >= 0) atomicOr(&reach[lr.x >> 5], 1u << (lr.x & 31));
                if (lr.y >= 0) atomicOr(&reach[lr.y >> 5], 1u << (lr.y & 31));
            }
        }
        __syncthreads();   // drain this wave's DS queue -> atomics visible
    }

    // ---- write int32 0/1 mask (int4 stores, 32 iters/lane) ----
    {
        int4* o4 = (int4*)out;
        const int nv = n / 4;
        for (int i = lane; i < nv; i += BLK) {
            unsigned int w = reach[i >> 3];
            int sh = (i & 7) * 4;
            o4[i] = make_int4((int)((w >> (sh + 0)) & 1u),
                              (int)((w >> (sh + 1)) & 1u),
                              (int)((w >> (sh + 2)) & 1u),
                              (int)((w >> (sh + 3)) & 1u));
        }
    }
}

extern "C" void kernel_launch(void* const* d_in, const int* in_sizes, int n_in,
                              void* d_out, int out_size, void* d_ws, size_t ws_size,
                              hipStream_t stream)
{
    // inputs: 0 = thresholds (f32, unused by reference), 1 = left, 2 = right
    const int* left  = (const int*)d_in[1];
    const int* right = (const int*)d_in[2];
    int* out = (int*)d_out;
    const int n = in_sizes[1];

    dag_reach_kernel<<<1, BLK, 0, stream>>>(left, right, out, n);
}

// Round 5
// 74.417 us; speedup vs baseline: 1.3805x; 1.3805x over previous
//
#include <hip/hip_runtime.h>

// DAG reachability closure from node 0 (N=8192, <=2 children, -1 = leaf).
// Reference's N relaxation steps == transitive closure; we BFS to fixpoint.
//
// R2(1024t,scan)=~25us, R3(256t,scan)=~37us, R4(64t,scan)=~52us kernel time:
// the bitmask-SCAN structure serializes expansion inside the owning thread
// (dependent ds_read chains), so width ruled. This round: work-efficient
// FRONTIER QUEUE in LDS — work distributed by frontier node, not word owner.
//   - single monotone queue (node enters once; atomicOr-return visited test)
//   - per pass: process frontier[start,end) strided over 256 threads;
//     iterations independent -> ds_reads pipeline; push via atomicAdd slot
//   - 2 barriers/pass make start/end uniform (read of qcount protected from
//     next pass's pushes)
//   - edges staged interleaved int2 in LDS (64 KB); queue 32 KB; mask 1 KB
// Output: int32 0/1 (harness materializes the bool mask as int32).

#define NMAX 8192
#define BLK  256

__global__ __launch_bounds__(BLK) void dag_reach_kernel(
    const int* __restrict__ left,
    const int* __restrict__ right,
    int* __restrict__ out,
    int n)
{
    __shared__ int2         sLR[NMAX];          // (left,right) per node
    __shared__ unsigned int visited[NMAX / 32]; // 256 words
    __shared__ int          frontier[NMAX];     // monotone BFS queue
    __shared__ int          s_qcount;

    const int tid = threadIdx.x;

    // ---- stage edges: int4 global loads, int2 LDS writes ----
    {
        const int4* l4 = (const int4*)left;
        const int4* r4 = (const int4*)right;
        const int nv = n / 4;
        for (int i = tid; i < nv; i += BLK) {
            int4 l = l4[i];
            int4 r = r4[i];
            int b = i * 4;
            sLR[b + 0] = make_int2(l.x, r.x);
            sLR[b + 1] = make_int2(l.y, r.y);
            sLR[b + 2] = make_int2(l.z, r.z);
            sLR[b + 3] = make_int2(l.w, r.w);
        }
    }
    for (int i = tid; i < NMAX / 32; i += BLK) visited[i] = 0u;
    if (tid == 0) { visited[0] = 1u; frontier[0] = 0; s_qcount = 1; }
    __syncthreads();

    // ---- frontier-queue BFS to fixpoint ----
    int start = 0, end = 1;
    while (start < end) {
        for (int i = start + tid; i < end; i += BLK) {
            int node = frontier[i];                 // ds_read (independent)
            int2 lr = sLR[node];                    // ds_read_b64 (pipelined)
            if (lr.x >= 0) {
                unsigned int bit = 1u << (lr.x & 31);
                unsigned int old = atomicOr(&visited[lr.x >> 5], bit);
                if (!(old & bit))
                    frontier[atomicAdd(&s_qcount, 1)] = lr.x;
            }
            if (lr.y >= 0) {
                unsigned int bit = 1u << (lr.y & 31);
                unsigned int old = atomicOr(&visited[lr.y >> 5], bit);
                if (!(old & bit))
                    frontier[atomicAdd(&s_qcount, 1)] = lr.y;
            }
        }
        __syncthreads();            // B1: all pushes of this level done
        start = end;
        end = s_qcount;             // uniform read across block
        __syncthreads();            // B2: protect read from next level's pushes
    }

    // ---- write int32 0/1 mask (int4 stores) ----
    {
        int4* o4 = (int4*)out;
        const int nv = n / 4;
        for (int i = tid; i < nv; i += BLK) {
            unsigned int w = visited[i >> 3];
            int sh = (i & 7) * 4;
            o4[i] = make_int4((int)((w >> (sh + 0)) & 1u),
                              (int)((w >> (sh + 1)) & 1u),
                              (int)((w >> (sh + 2)) & 1u),
                              (int)((w >> (sh + 3)) & 1u));
        }
    }
}

extern "C" void kernel_launch(void* const* d_in, const int* in_sizes, int n_in,
                              void* d_out, int out_size, void* d_ws, size_t ws_size,
                              hipStream_t stream)
{
    // inputs: 0 = thresholds (f32, unused by reference), 1 = left, 2 = right
    const int* left  = (const int*)d_in[1];
    const int* right = (const int*)d_in[2];
    int* out = (int*)d_out;
    const int n = in_sizes[1];

    dag_reach_kernel<<<1, BLK, 0, stream>>>(left, right, out, n);
}